// Round 10
// baseline (964.889 us; speedup 1.0000x reference)
//
#include <hip/hip_runtime.h>
#include <hip/hip_bf16.h>
#include <stdint.h>

#define BB 4
#define NN 1024
#define DD 1024
#define HH 16
#define HDIM 64
#define KVHH 4
#define MM (BB * NN)  // 4096 token rows

typedef __hip_bfloat16 bf16;
typedef __attribute__((ext_vector_type(8))) short bf16x8;  // 8 bf16 = 4 VGPR
typedef __attribute__((ext_vector_type(4))) float f32x4;

// Fragment-major layout ("frag"): for a matrix M[R][C], element (r,c) lives at
//   ((r>>4)*(C/8) + (c>>3))*128 + (r&15)*8 + (c&7)
// so a wave's 16x8 MFMA fragment (rows r0..r0+15, chunk c0..c0+7) is one
// contiguous 1KB block, loadable as lane-linear dwordx4 (lane = quad*16+l15
// reads offset lane*8 elements).

__device__ __forceinline__ float b2f(unsigned short u) {
  return __uint_as_float(((unsigned)u) << 16);
}
__device__ __forceinline__ unsigned short f2b(float x) {
  bf16 h = __float2bfloat16(x);
  unsigned short u;
  __builtin_memcpy(&u, &h, 2);
  return u;
}
__device__ __forceinline__ f32x4 mfma16(bf16x8 a, bf16x8 b, f32x4 c) {
  return __builtin_amdgcn_mfma_f32_16x16x32_bf16(a, b, c, 0, 0, 0);
}
__device__ __forceinline__ void gl_lds16(const short* g, short* l) {
  __builtin_amdgcn_global_load_lds(
      (const __attribute__((address_space(1))) unsigned*)g,
      (__attribute__((address_space(3))) unsigned*)l, 16, 0, 0);
}

// ---------------------------------------------------------------------------
// z=0..2: weight transposes W (K x N fp32) -> WT (N x K bf16) row-major (for
// gemm_proj's gl_lds staging). z=3: Wo -> WoT in FRAG-MAJOR. z=4: bias.
// z=5: x fp32 -> bf16 row-major.
// ---------------------------------------------------------------------------
__global__ __launch_bounds__(256) void transpose_all(
    const float* __restrict__ Wq, const float* __restrict__ Wkv,
    const float* __restrict__ Wg, const float* __restrict__ Wo,
    const float* __restrict__ bg, const float* __restrict__ x,
    short* __restrict__ WcT, short* __restrict__ WoT,
    float* __restrict__ bias, short* __restrict__ xb) {
  const int z = blockIdx.z;
  if (z == 4) {
    if (blockIdx.y == 0 && blockIdx.x < 10) {
      int i = blockIdx.x * 256 + threadIdx.x;
      if (i < 2560) bias[i] = (i >= 1024 && i < 2048) ? bg[i - 1024] : 0.f;
    }
    return;
  }
  if (z == 5) {  // x convert: row-major bf16
    int base = (blockIdx.y * 16 + blockIdx.x) * 256 + threadIdx.x;
#pragma unroll
    for (int it = 0; it < 16; ++it) {
      int i = base + it * 65536;
      float4 v = *(const float4*)&x[(size_t)i * 4];
      ushort4 o;
      o.x = f2b(v.x); o.y = f2b(v.y); o.z = f2b(v.z); o.w = f2b(v.w);
      *(ushort4*)&xb[(size_t)i * 4] = o;
    }
    return;
  }
  const float* W;
  short* WT;
  int N = 1024;
  const int K = 1024;
  if (z == 0) { W = Wq; WT = WcT; }
  else if (z == 1) { W = Wg; WT = WcT + 1048576; }
  else if (z == 2) {
    W = Wkv; WT = WcT + 2097152; N = 512;
    if (blockIdx.x >= 8) return;  // uniform early-out, before any sync
  } else { W = Wo; WT = WoT; }

  __shared__ short T[64 * 68];
  const int tid = threadIdx.x;
  const int n0 = blockIdx.x * 64, k0 = blockIdx.y * 64;
  {
    int i0 = tid >> 4, j4 = (tid & 15) * 4;
#pragma unroll
    for (int ii = 0; ii < 4; ++ii) {
      int i = i0 + 16 * ii;
      float4 w = *(const float4*)&W[(size_t)(k0 + i) * N + n0 + j4];
      ushort4 o;
      o.x = f2b(w.x); o.y = f2b(w.y); o.z = f2b(w.z); o.w = f2b(w.w);
      *(ushort4*)&T[i * 68 + j4] = o;
    }
  }
  __syncthreads();
  {
    int n = tid >> 2, k16 = (tid & 3) * 16;
    short tmp[16];
#pragma unroll
    for (int kk = 0; kk < 16; ++kk) tmp[kk] = T[(k16 + kk) * 68 + n];
    if (z == 3) {  // frag-major: rows = n (out col), k dim = 1024
      int nt = (n0 + n) >> 4, nl = n & 15;
#pragma unroll
      for (int s = 0; s < 16; s += 4) {
        int k = k0 + k16 + s;
        *(ushort4*)&WoT[(size_t)nt * 16384 + (k >> 3) * 128 + nl * 8 + (k & 7)] =
            *(const ushort4*)&tmp[s];
      }
    } else {
      short* dst = WT + (size_t)(n0 + n) * K + k0 + k16;
#pragma unroll
      for (int s = 0; s < 16; s += 4) *(ushort4*)&dst[s] = *(const ushort4*)&tmp[s];
    }
  }
}

// ---------------------------------------------------------------------------
// Fused projection GEMM (r7-proven loop): 64x128 tile, BK=32, dbuf gl_lds.
// Epilogue scatters to FRAG-MAJOR q/k/v (+row-major gate):
//   q: per (b,h) 65536-elem frag block   [tok x 64d]
//   k: per (b,kvh) 65536-elem frag block [tok x 64d]
//   v: per (b,kvh) 65536-elem frag block [64d x tok]  (transposed)
// ---------------------------------------------------------------------------
__global__ __launch_bounds__(256, 5) void gemm_proj(
    const short* __restrict__ A, const short* __restrict__ WT,
    const float* __restrict__ bias, short* __restrict__ qf_,
    short* __restrict__ gc, short* __restrict__ kf_, short* __restrict__ vf_) {
  __shared__ short As[2][64 * 32];
  __shared__ short Bs[2][128 * 32];
  const int tid = threadIdx.x;
  const int wave = tid >> 6, lane = tid & 63, l15 = lane & 15, quad = lane >> 4;
  const int m0 = blockIdx.y * 64, n0 = blockIdx.x * 128;
  const int wm = (wave & 1) * 32, wn = (wave >> 1) * 64;
  const int arow = tid >> 2, ac = (tid & 3) * 8;
  const short* asrc = A + (size_t)(m0 + arow) * 1024 + ac;
  const short* bsrc = WT + (size_t)(n0 + arow) * 1024 + ac;

  gl_lds16(asrc, &As[0][wave * 512]);
  gl_lds16(bsrc, &Bs[0][wave * 512]);
  gl_lds16(bsrc + 64 * 1024, &Bs[0][wave * 512 + 2048]);

  f32x4 acc[2][4] = {};
  for (int k = 0; k < 32; ++k) {
    const int cur = k & 1;
    __syncthreads();
    if (k < 31) {
      const short* ap = asrc + (k + 1) * 32;
      const short* bp = bsrc + (k + 1) * 32;
      gl_lds16(ap, &As[1 - cur][wave * 512]);
      gl_lds16(bp, &Bs[1 - cur][wave * 512]);
      gl_lds16(bp + 64 * 1024, &Bs[1 - cur][wave * 512 + 2048]);
    }
    bf16x8 af[2], bfr[4];
#pragma unroll
    for (int i = 0; i < 2; ++i)
      af[i] = *(const bf16x8*)&As[cur][(wm + 16 * i + l15) * 32 + quad * 8];
#pragma unroll
    for (int j = 0; j < 4; ++j)
      bfr[j] = *(const bf16x8*)&Bs[cur][(wn + 16 * j + l15) * 32 + quad * 8];
#pragma unroll
    for (int i = 0; i < 2; ++i)
#pragma unroll
      for (int j = 0; j < 4; ++j) acc[i][j] = mfma16(af[i], bfr[j], acc[i][j]);
  }
#pragma unroll
  for (int j = 0; j < 4; ++j) {
    int col = n0 + wn + 16 * j + l15;
    float bv = bias[col];
    int reg = col >> 6;  // head-slot 0..39
    int d = col & 63;
#pragma unroll
    for (int i = 0; i < 2; ++i) {
#pragma unroll
      for (int r = 0; r < 4; ++r) {
        int row = m0 + wm + 16 * i + quad * 4 + r;
        int b = row >> 10, tok = row & 1023;
        unsigned short v = f2b(acc[i][j][r] + bv);
        if (reg < 16) {
          ((unsigned short*)qf_)[(size_t)(b * 16 + reg) * 65536 +
                                 ((tok >> 4) * 8 + (d >> 3)) * 128 +
                                 (tok & 15) * 8 + (d & 7)] = v;
        } else if (reg < 32) {
          ((unsigned short*)gc)[((size_t)((b * 16 + reg - 16) * 1024 + tok)) * 64 + d] = v;
        } else if (reg < 36) {
          ((unsigned short*)kf_)[(size_t)(b * 4 + reg - 32) * 65536 +
                                 ((tok >> 4) * 8 + (d >> 3)) * 128 +
                                 (tok & 15) * 8 + (d & 7)] = v;
        } else {
          ((unsigned short*)vf_)[(size_t)(b * 4 + reg - 36) * 65536 +
                                 (((d >> 4) * 128 + (tok >> 3)) * 16 + (d & 15)) * 8 +
                                 (tok & 7)] = v;
        }
      }
    }
  }
}

// ---------------------------------------------------------------------------
// Output projection, round 10: ZERO-LDS, ZERO-BARRIER direct-fragment GEMM.
// A = gated (frag-major, written by attn), B = WoT (frag-major). 64x64 tile,
// 4 waves = 2x2 of 32x32. Per K=32 step: 4 contiguous 1KB loads + 4 MFMA.
// ---------------------------------------------------------------------------
__global__ __launch_bounds__(256, 4) void gemm_out3(
    const short* __restrict__ afrag, const short* __restrict__ bfrag,
    float* __restrict__ Cout) {
  const int tid = threadIdx.x;
  const int w = tid >> 6, lane = tid & 63, l15 = lane & 15, quad = lane >> 4;
  const int m0 = blockIdx.y * 64, n0 = blockIdx.x * 64;
  const int wm = (w & 1) * 32, wn = (w >> 1) * 32;
  const short* a0 = afrag + (size_t)((m0 + wm) >> 4) * 16384 + lane * 8;
  const short* a1 = a0 + 16384;
  const short* b0 = bfrag + (size_t)((n0 + wn) >> 4) * 16384 + lane * 8;
  const short* b1 = b0 + 16384;

  f32x4 acc[2][2] = {};
#pragma unroll 4
  for (int s = 0; s < 32; ++s) {
    bf16x8 af0 = *(const bf16x8*)(a0 + s * 512);
    bf16x8 af1 = *(const bf16x8*)(a1 + s * 512);
    bf16x8 bf0 = *(const bf16x8*)(b0 + s * 512);
    bf16x8 bf1 = *(const bf16x8*)(b1 + s * 512);
    acc[0][0] = mfma16(af0, bf0, acc[0][0]);
    acc[0][1] = mfma16(af0, bf1, acc[0][1]);
    acc[1][0] = mfma16(af1, bf0, acc[1][0]);
    acc[1][1] = mfma16(af1, bf1, acc[1][1]);
  }
#pragma unroll
  for (int j = 0; j < 2; ++j) {
    int col = n0 + wn + 16 * j + l15;
#pragma unroll
    for (int i = 0; i < 2; ++i) {
#pragma unroll
      for (int r = 0; r < 4; ++r) {
        int row = m0 + wm + 16 * i + quad * 4 + r;
        Cout[(size_t)row * 1024 + col] = acc[i][j][r];
      }
    }
  }
}

// ---------------------------------------------------------------------------
// MFMA flash attention + gate, round 10: direct-register K/V/Q fragments.
// Block: (qt, b*16+h), 64 q rows, 4 waves. Wave owns 16 keys (S) / 16 d (PV).
// K/V/Q frags load straight from frag-major global (contiguous 1KB dwordx4,
// software-pipelined one kt ahead; no LDS staging). P via r7's swizzled LDS
// round-trip, double-buffered -> ONE barrier per kt. Fixed-max softmax.
// Epilogue writes gated in FRAG-MAJOR (gemm_out3's A operand).
// ---------------------------------------------------------------------------
__global__ __launch_bounds__(256, 4) void attn_mfma7(
    const short* __restrict__ qfrag, const short* __restrict__ gc,
    const short* __restrict__ kfrag, const short* __restrict__ vfrag,
    unsigned short* __restrict__ gated) {
  __shared__ short Ps[2][64 * 64];
  __shared__ float Lpart[4 * 64];
  __shared__ float Lq[64];
  const int tid = threadIdx.x;
  const int w = tid >> 6, lane = tid & 63, l15 = lane & 15, quad = lane >> 4;
  const int qt = blockIdx.x, bh = blockIdx.y, b = bh >> 4, h = bh & 15, kvh = h >> 2;
  const int fs = l15 & 7;                // P swizzle key (r7-proven scheme)
  const int s0 = (quad ^ fs) * 8;
  const int s1 = ((4 + quad) ^ fs) * 8;
  const int pslot = ((2 * w + (quad >> 1)) ^ fs) * 8 + (quad & 1) * 4;

  // Q B-frags: loop-invariant, contiguous 1KB loads
  const short* qb = qfrag + (size_t)(b * 16 + h) * 65536 + (size_t)qt * 4096 + lane * 8;
  bf16x8 qf[4][2];
#pragma unroll
  for (int jq = 0; jq < 4; ++jq) {
    qf[jq][0] = *(const bf16x8*)(qb + jq * 1024);
    qf[jq][1] = *(const bf16x8*)(qb + jq * 1024 + 512);
  }

  // K/V frag bases for this wave (contiguous 1KB per frag pair)
  const short* kb = kfrag + (size_t)(b * 4 + kvh) * 65536 + w * 1024 + lane * 8;
  const short* vb = vfrag + (size_t)(b * 4 + kvh) * 65536 + w * 16384 + lane * 8;

  f32x4 oacc[4];
  float ls[4];
#pragma unroll
  for (int jq = 0; jq < 4; ++jq) {
    oacc[jq] = (f32x4){0.f, 0.f, 0.f, 0.f};
    ls[jq] = 0.f;
  }

  bf16x8 kfr[2][2], vfr[2][2];
  kfr[0][0] = *(const bf16x8*)(kb);
  kfr[0][1] = *(const bf16x8*)(kb + 512);
  vfr[0][0] = *(const bf16x8*)(vb);
  vfr[0][1] = *(const bf16x8*)(vb + 512);

#pragma unroll 2
  for (int kt = 0; kt < 16; ++kt) {
    const int pb = kt & 1, nb = pb ^ 1;
    if (kt < 15) {  // prefetch kt+1 frags into the other register set
      kfr[nb][0] = *(const bf16x8*)(kb + (kt + 1) * 4096);
      kfr[nb][1] = *(const bf16x8*)(kb + (kt + 1) * 4096 + 512);
      vfr[nb][0] = *(const bf16x8*)(vb + (kt + 1) * 1024);
      vfr[nb][1] = *(const bf16x8*)(vb + (kt + 1) * 1024 + 512);
    }
    short* ps = &Ps[pb][0];
    // ---- S phase: S^T = K·Q^T (C: key = 4quad+r, q = l15); P -> LDS buf pb
#pragma unroll
    for (int jq = 0; jq < 4; ++jq) {
      f32x4 st = mfma16(kfr[pb][0], qf[jq][0], (f32x4){0.f, 0.f, 0.f, 0.f});
      st = mfma16(kfr[pb][1], qf[jq][1], st);
      // exp(s/8) = exp2(s * 0.125*log2e)
      float p0 = exp2f(st[0] * 0.18033688f);
      float p1 = exp2f(st[1] * 0.18033688f);
      float p2 = exp2f(st[2] * 0.18033688f);
      float p3 = exp2f(st[3] * 0.18033688f);
      ls[jq] += (p0 + p1) + (p2 + p3);
      uint2 dd;
      dd.x = (unsigned)f2b(p0) | ((unsigned)f2b(p1) << 16);
      dd.y = (unsigned)f2b(p2) | ((unsigned)f2b(p3) << 16);
      *(uint2*)&ps[(16 * jq + l15) * 64 + pslot] = dd;
    }
    __syncthreads();  // P(kt) visible; also fences buf reuse two kts apart
    // ---- PV phase: wave owns d-subtile w
#pragma unroll
    for (int jq = 0; jq < 4; ++jq) {
      bf16x8 pf0 = *(const bf16x8*)&ps[(16 * jq + l15) * 64 + s0];
      bf16x8 pf1 = *(const bf16x8*)&ps[(16 * jq + l15) * 64 + s1];
      oacc[jq] = mfma16(pf0, vfr[pb][0], oacc[jq]);
      oacc[jq] = mfma16(pf1, vfr[pb][1], oacc[jq]);
    }
  }

  // l reduction: quad-reduce in-wave, then across waves via LDS
#pragma unroll
  for (int jq = 0; jq < 4; ++jq) {
    ls[jq] += __shfl_xor(ls[jq], 16);
    ls[jq] += __shfl_xor(ls[jq], 32);
  }
  if (quad == 0) {
#pragma unroll
    for (int jq = 0; jq < 4; ++jq) Lpart[w * 64 + 16 * jq + l15] = ls[jq];
  }
  __syncthreads();
  if (tid < 64)
    Lq[tid] = Lpart[tid] + Lpart[64 + tid] + Lpart[128 + tid] + Lpart[192 + tid];
  __syncthreads();

  // epilogue: O rows q = 16jq+4quad+r, cols d = 16w+l15; gate; FRAG-MAJOR store
  const int C = h * 64 + 16 * w + l15;  // output column 0..1023
  const int Ct = (C >> 3) * 128 + (C & 7);
#pragma unroll
  for (int jq = 0; jq < 4; ++jq) {
#pragma unroll
    for (int r = 0; r < 4; ++r) {
      int qloc = 16 * jq + 4 * quad + r;
      float lv = Lq[qloc];
      float gv = b2f(((const unsigned short*)gc)[
          ((size_t)((b * 16 + h) * 1024) + qt * 64 + qloc) * 64 + 16 * w + l15]);
      int Rt = b * 64 + qt * 4 + jq;  // (global row)>>4
      gated[(size_t)Rt * 16384 + Ct + (4 * quad + r) * 8] =
          f2b(oacc[jq][r] / lv * gv);
    }
  }
}

// ---------------------------------------------------------------------------
extern "C" void kernel_launch(void* const* d_in, const int* in_sizes, int n_in,
                              void* d_out, int out_size, void* d_ws,
                              size_t ws_size, hipStream_t stream) {
  const float* x = (const float*)d_in[0];
  const float* Wq = (const float*)d_in[1];
  const float* Wkv = (const float*)d_in[2];
  const float* Wg = (const float*)d_in[3];
  const float* bg = (const float*)d_in[4];
  const float* Wo = (const float*)d_in[5];
  float* out = (float*)d_out;

  // ws layout (short elems): ~36.6 MB total
  short* ws = (short*)d_ws;
  short* xb = ws;                     // 4.19M (x bf16; later aliased as gated frag)
  short* WcT = xb + 4194304;          // 2.62M (W^T combined q|g|kv, row-major)
  short* WoT = WcT + 2621440;         // 1.05M (frag-major)
  short* qfr = WoT + 1048576;         // 4.19M  q frag-major per (b,h)
  short* gc = qfr + 4194304;          // 4.19M  gate row-major [b,h,tok,d]
  short* kfr = gc + 4194304;          // 1.05M  k frag-major per (b,kvh)
  short* vfr = kfr + 1048576;         // 1.05M  v^T frag-major per (b,kvh)
  float* bias_f32 = (float*)(vfr + 1048576);  // 2560 f32

  dim3 blk(256);
  transpose_all<<<dim3(16, 16, 6), blk, 0, stream>>>(Wq, Wkv, Wg, Wo, bg, x,
                                                     WcT, WoT, bias_f32, xb);
  gemm_proj<<<dim3(20, 64), blk, 0, stream>>>(xb, WcT, bias_f32, qfr, gc, kfr, vfr);
  // attention + gate -> gated frag-major (aliases xb)
  attn_mfma7<<<dim3(16, 64), blk, 0, stream>>>(qfr, gc, kfr, vfr,
                                               (unsigned short*)xb);
  // output projection: zero-LDS direct-fragment GEMM
  gemm_out3<<<dim3(16, 64), blk, 0, stream>>>(xb, WoT, out);
}

// Round 11
// 187.238 us; speedup vs baseline: 5.1533x; 5.1533x over previous
//
#include <hip/hip_runtime.h>
#include <hip/hip_bf16.h>
#include <stdint.h>

#define BB 4
#define NN 1024
#define DD 1024
#define HH 16
#define HDIM 64
#define KVHH 4
#define MM (BB * NN)  // 4096 token rows

typedef __hip_bfloat16 bf16;
typedef __attribute__((ext_vector_type(8))) short bf16x8;  // 8 bf16 = 4 VGPR
typedef __attribute__((ext_vector_type(4))) float f32x4;

__device__ __forceinline__ float b2f(unsigned short u) {
  return __uint_as_float(((unsigned)u) << 16);
}
__device__ __forceinline__ unsigned short f2b(float x) {
  bf16 h = __float2bfloat16(x);
  unsigned short u;
  __builtin_memcpy(&u, &h, 2);
  return u;
}
__device__ __forceinline__ f32x4 mfma16(bf16x8 a, bf16x8 b, f32x4 c) {
  return __builtin_amdgcn_mfma_f32_16x16x32_bf16(a, b, c, 0, 0, 0);
}
__device__ __forceinline__ void gl_lds16(const short* g, short* l) {
  __builtin_amdgcn_global_load_lds(
      (const __attribute__((address_space(1))) unsigned*)g,
      (__attribute__((address_space(3))) unsigned*)l, 16, 0, 0);
}

// ---------------------------------------------------------------------------
// z=0..3: weight transposes W (K x N fp32) -> WT (N x K bf16), 64x64 tiles.
// z=4: combined bias build. z=5: x fp32 -> bf16 convert.
// ---------------------------------------------------------------------------
__global__ __launch_bounds__(256) void transpose_all(
    const float* __restrict__ Wq, const float* __restrict__ Wkv,
    const float* __restrict__ Wg, const float* __restrict__ Wo,
    const float* __restrict__ bg, const float* __restrict__ x,
    short* __restrict__ WcT, short* __restrict__ WoT,
    float* __restrict__ bias, short* __restrict__ xb) {
  const int z = blockIdx.z;
  if (z == 4) {  // combined bias: [0,1024)=0, [1024,2048)=bg, [2048,2560)=0
    if (blockIdx.y == 0 && blockIdx.x < 10) {
      int i = blockIdx.x * 256 + threadIdx.x;
      if (i < 2560) bias[i] = (i >= 1024 && i < 2048) ? bg[i - 1024] : 0.f;
    }
    return;
  }
  if (z == 5) {  // x convert: 256 blocks x 256 threads x 16 float4
    int base = (blockIdx.y * 16 + blockIdx.x) * 256 + threadIdx.x;
#pragma unroll
    for (int it = 0; it < 16; ++it) {
      int i = base + it * 65536;
      float4 v = *(const float4*)&x[(size_t)i * 4];
      ushort4 o;
      o.x = f2b(v.x); o.y = f2b(v.y); o.z = f2b(v.z); o.w = f2b(v.w);
      *(ushort4*)&xb[(size_t)i * 4] = o;
    }
    return;
  }
  const float* W;
  short* WT;
  int N = 1024;
  const int K = 1024;
  if (z == 0) { W = Wq; WT = WcT; }
  else if (z == 1) { W = Wg; WT = WcT + 1048576; }
  else if (z == 2) {
    W = Wkv; WT = WcT + 2097152; N = 512;
    if (blockIdx.x >= 8) return;  // uniform early-out, before any sync
  } else { W = Wo; WT = WoT; }

  __shared__ short T[64 * 68];
  const int tid = threadIdx.x;
  const int n0 = blockIdx.x * 64, k0 = blockIdx.y * 64;
  {
    int i0 = tid >> 4, j4 = (tid & 15) * 4;
#pragma unroll
    for (int ii = 0; ii < 4; ++ii) {
      int i = i0 + 16 * ii;
      float4 w = *(const float4*)&W[(size_t)(k0 + i) * N + n0 + j4];
      ushort4 o;
      o.x = f2b(w.x); o.y = f2b(w.y); o.z = f2b(w.z); o.w = f2b(w.w);
      *(ushort4*)&T[i * 68 + j4] = o;
    }
  }
  __syncthreads();
  {
    int n = tid >> 2, k16 = (tid & 3) * 16;
    short tmp[16];
#pragma unroll
    for (int kk = 0; kk < 16; ++kk) tmp[kk] = T[(k16 + kk) * 68 + n];
    short* dst = WT + (size_t)(n0 + n) * K + k0 + k16;
#pragma unroll
    for (int s = 0; s < 16; s += 4) *(ushort4*)&dst[s] = *(const ushort4*)&tmp[s];
  }
}

// ---------------------------------------------------------------------------
// Fused projection GEMM: 64x128 tile (grid 20x64 = 1280 blocks = 5/CU), BK=32,
// double-buffered gl_lds. Epilogue diverts to compact head-major buffers
// (row-major, coalesced writes — frag-major scatter is a 17x write-amp trap).
// ---------------------------------------------------------------------------
__global__ __launch_bounds__(256, 5) void gemm_proj(
    const short* __restrict__ A, const short* __restrict__ WT,
    const float* __restrict__ bias, short* __restrict__ qc,
    short* __restrict__ gc, short* __restrict__ kc, short* __restrict__ vt) {
  __shared__ short As[2][64 * 32];
  __shared__ short Bs[2][128 * 32];
  const int tid = threadIdx.x;
  const int wave = tid >> 6, lane = tid & 63, l15 = lane & 15, quad = lane >> 4;
  const int m0 = blockIdx.y * 64, n0 = blockIdx.x * 128;
  const int wm = (wave & 1) * 32, wn = (wave >> 1) * 64;
  const int arow = tid >> 2, ac = (tid & 3) * 8;
  const short* asrc = A + (size_t)(m0 + arow) * 1024 + ac;
  const short* bsrc = WT + (size_t)(n0 + arow) * 1024 + ac;

  gl_lds16(asrc, &As[0][wave * 512]);
  gl_lds16(bsrc, &Bs[0][wave * 512]);
  gl_lds16(bsrc + 64 * 1024, &Bs[0][wave * 512 + 2048]);

  f32x4 acc[2][4] = {};
  for (int k = 0; k < 32; ++k) {
    const int cur = k & 1;
    __syncthreads();  // stage(k) landed; iter k-1 LDS reads drained
    if (k < 31) {
      const short* ap = asrc + (k + 1) * 32;
      const short* bp = bsrc + (k + 1) * 32;
      gl_lds16(ap, &As[1 - cur][wave * 512]);
      gl_lds16(bp, &Bs[1 - cur][wave * 512]);
      gl_lds16(bp + 64 * 1024, &Bs[1 - cur][wave * 512 + 2048]);
    }
    bf16x8 af[2], bfr[4];
#pragma unroll
    for (int i = 0; i < 2; ++i)
      af[i] = *(const bf16x8*)&As[cur][(wm + 16 * i + l15) * 32 + quad * 8];
#pragma unroll
    for (int j = 0; j < 4; ++j)
      bfr[j] = *(const bf16x8*)&Bs[cur][(wn + 16 * j + l15) * 32 + quad * 8];
#pragma unroll
    for (int i = 0; i < 2; ++i)
#pragma unroll
      for (int j = 0; j < 4; ++j) acc[i][j] = mfma16(af[i], bfr[j], acc[i][j]);
  }
#pragma unroll
  for (int j = 0; j < 4; ++j) {
    int col = n0 + wn + 16 * j + l15;
    float bv = bias[col];
    int reg = col >> 6;  // head-slot 0..39 (uniform across the 16 lanes)
    int d = col & 63;
#pragma unroll
    for (int i = 0; i < 2; ++i) {
#pragma unroll
      for (int r = 0; r < 4; ++r) {
        int row = m0 + wm + 16 * i + quad * 4 + r;
        int b = row >> 10, tok = row & 1023;
        unsigned short v = f2b(acc[i][j][r] + bv);
        if (reg < 16)
          ((unsigned short*)qc)[((size_t)((b * 16 + reg) * 1024 + tok)) * 64 + d] = v;
        else if (reg < 32)
          ((unsigned short*)gc)[((size_t)((b * 16 + reg - 16) * 1024 + tok)) * 64 + d] = v;
        else if (reg < 36)
          ((unsigned short*)kc)[((size_t)((b * 4 + reg - 32) * 1024 + tok)) * 64 + d] = v;
        else
          ((unsigned short*)vt)[((size_t)((b * 4 + reg - 36) * 64 + d)) * 1024 + tok] = v;
      }
    }
  }
}

// ---------------------------------------------------------------------------
// Output-projection GEMM (r7-proven): 64x64 tile, grid 16x64 = 1024 blocks,
// BK=32, double-buffered gl_lds, 4 waves = 2x2 of (32m x 32n).
// ---------------------------------------------------------------------------
__global__ __launch_bounds__(256, 4) void gemm_out(
    const short* __restrict__ A, const short* __restrict__ WT,
    float* __restrict__ Cout) {
  __shared__ short As[2][64 * 32];
  __shared__ short Bs[2][64 * 32];
  const int tid = threadIdx.x;
  const int wave = tid >> 6, lane = tid & 63, l15 = lane & 15, quad = lane >> 4;
  const int m0 = blockIdx.y * 64, n0 = blockIdx.x * 64;
  const int wm = (wave & 1) * 32, wn = (wave >> 1) * 32;
  const int arow = tid >> 2, ac = (tid & 3) * 8;
  const short* asrc = A + (size_t)(m0 + arow) * 1024 + ac;
  const short* bsrc = WT + (size_t)(n0 + arow) * 1024 + ac;

  gl_lds16(asrc, &As[0][wave * 512]);
  gl_lds16(bsrc, &Bs[0][wave * 512]);

  f32x4 acc[2][2] = {};
  for (int k = 0; k < 32; ++k) {
    const int cur = k & 1;
    __syncthreads();
    if (k < 31) {
      gl_lds16(asrc + (k + 1) * 32, &As[1 - cur][wave * 512]);
      gl_lds16(bsrc + (k + 1) * 32, &Bs[1 - cur][wave * 512]);
    }
    bf16x8 af[2], bfr[2];
#pragma unroll
    for (int i = 0; i < 2; ++i)
      af[i] = *(const bf16x8*)&As[cur][(wm + 16 * i + l15) * 32 + quad * 8];
#pragma unroll
    for (int j = 0; j < 2; ++j)
      bfr[j] = *(const bf16x8*)&Bs[cur][(wn + 16 * j + l15) * 32 + quad * 8];
#pragma unroll
    for (int i = 0; i < 2; ++i)
#pragma unroll
      for (int j = 0; j < 2; ++j) acc[i][j] = mfma16(af[i], bfr[j], acc[i][j]);
  }
#pragma unroll
  for (int j = 0; j < 2; ++j) {
    int col = n0 + wn + 16 * j + l15;
#pragma unroll
    for (int i = 0; i < 2; ++i) {
#pragma unroll
      for (int r = 0; r < 4; ++r) {
        int row = m0 + wm + 16 * i + quad * 4 + r;
        Cout[(size_t)row * 1024 + col] = acc[i][j][r];
      }
    }
  }
}

// ---------------------------------------------------------------------------
// MFMA flash attention + gate, round 11: r7 layouts + r10 loop structure.
// Block: (qt, b*16+h), 64 q rows, 4 waves. Wave w owns keys [16w,16w+16) in
// the S phase and d-subtile w in PV. K/V MFMA fragments load DIRECTLY from
// row-major kc / vt global into registers (16 rows x 64B segments per load,
// L2-hot, register-double-buffered one kt ahead — no LDS staging, no vmcnt
// barrier coupling). P via swizzled LDS round-trip, double-buffered ->
// ONE barrier per kt. Fixed-max softmax. Coalesced row-major gated store.
// ---------------------------------------------------------------------------
__global__ __launch_bounds__(256, 4) void attn_mfma8(
    const short* __restrict__ qc, const short* __restrict__ gc,
    const short* __restrict__ kc, const short* __restrict__ vt,
    unsigned short* __restrict__ gated) {
  __shared__ short Ps[2][64 * 64];
  __shared__ float Lpart[4 * 64];
  __shared__ float Lq[64];
  const int tid = threadIdx.x;
  const int w = tid >> 6, lane = tid & 63, l15 = lane & 15, quad = lane >> 4;
  const int qt = blockIdx.x, bh = blockIdx.y, b = bh >> 4, h = bh & 15, kvh = h >> 2;
  const int fs = l15 & 7;                // P swizzle key (r7-proven scheme)
  const int s0 = (quad ^ fs) * 8;
  const int s1 = ((4 + quad) ^ fs) * 8;
  const int pslot = ((2 * w + (quad >> 1)) ^ fs) * 8 + (quad & 1) * 4;

  // Q B-frags (loop-invariant): row q = qt*64+16jq+l15, k = d = quad*8+i (+32)
  bf16x8 qf[4][2];
#pragma unroll
  for (int jq = 0; jq < 4; ++jq) {
    const short* qp =
        qc + ((size_t)((b * 16 + h) * 1024) + qt * 64 + 16 * jq + l15) * 64 + quad * 8;
    qf[jq][0] = *(const bf16x8*)qp;
    qf[jq][1] = *(const bf16x8*)(qp + 32);
  }

  // K A-frag base: row key = 16w+l15 of kc[b,kvh,tok,64]; k = d chunks
  const short* kb = kc + ((size_t)((b * 4 + kvh) * 1024) + 16 * w + l15) * 64 + quad * 8;
  // V B-frag base: row d = 16w+l15 of vt[b,kvh,d,tok]; k = key chunks
  const short* vb = vt + ((size_t)((b * 4 + kvh) * 64) + 16 * w + l15) * 1024 + quad * 8;

  f32x4 oacc[4];
  float ls[4];
#pragma unroll
  for (int jq = 0; jq < 4; ++jq) {
    oacc[jq] = (f32x4){0.f, 0.f, 0.f, 0.f};
    ls[jq] = 0.f;
  }

  // register double-buffer for K/V fragments
  bf16x8 kfr[2][2], vfr[2][2];
  kfr[0][0] = *(const bf16x8*)(kb);
  kfr[0][1] = *(const bf16x8*)(kb + 32);
  vfr[0][0] = *(const bf16x8*)(vb);
  vfr[0][1] = *(const bf16x8*)(vb + 32);

  for (int kt = 0; kt < 16; ++kt) {
    const int pb = kt & 1, nb = pb ^ 1;
    if (kt < 15) {  // prefetch kt+1 (kc advances 64 rows = 4096; vt 64 cols)
      const short* kp = kb + (size_t)(kt + 1) * 4096;
      const short* vp = vb + (size_t)(kt + 1) * 64;
      kfr[nb][0] = *(const bf16x8*)(kp);
      kfr[nb][1] = *(const bf16x8*)(kp + 32);
      vfr[nb][0] = *(const bf16x8*)(vp);
      vfr[nb][1] = *(const bf16x8*)(vp + 32);
    }
    short* ps = &Ps[pb][0];
    // ---- S phase: S^T = K·Q^T (C: key = 4quad+r, q = l15); P -> LDS buf pb
#pragma unroll
    for (int jq = 0; jq < 4; ++jq) {
      f32x4 st = mfma16(kfr[pb][0], qf[jq][0], (f32x4){0.f, 0.f, 0.f, 0.f});
      st = mfma16(kfr[pb][1], qf[jq][1], st);
      // exp(s/8) = exp2(s * 0.125*log2e)
      float p0 = exp2f(st[0] * 0.18033688f);
      float p1 = exp2f(st[1] * 0.18033688f);
      float p2 = exp2f(st[2] * 0.18033688f);
      float p3 = exp2f(st[3] * 0.18033688f);
      ls[jq] += (p0 + p1) + (p2 + p3);
      uint2 dd;
      dd.x = (unsigned)f2b(p0) | ((unsigned)f2b(p1) << 16);
      dd.y = (unsigned)f2b(p2) | ((unsigned)f2b(p3) << 16);
      *(uint2*)&ps[(16 * jq + l15) * 64 + pslot] = dd;
    }
    __syncthreads();  // P(kt) visible; buf pb reuse is 2 kts (=1 barrier) away
    // ---- PV phase: wave owns d-subtile w; A=P rows q, B=V^T rows d
#pragma unroll
    for (int jq = 0; jq < 4; ++jq) {
      bf16x8 pf0 = *(const bf16x8*)&ps[(16 * jq + l15) * 64 + s0];
      bf16x8 pf1 = *(const bf16x8*)&ps[(16 * jq + l15) * 64 + s1];
      oacc[jq] = mfma16(pf0, vfr[pb][0], oacc[jq]);
      oacc[jq] = mfma16(pf1, vfr[pb][1], oacc[jq]);
    }
  }

  // l reduction: quad-reduce in-wave, then across waves via LDS
#pragma unroll
  for (int jq = 0; jq < 4; ++jq) {
    ls[jq] += __shfl_xor(ls[jq], 16);
    ls[jq] += __shfl_xor(ls[jq], 32);
  }
  if (quad == 0) {
#pragma unroll
    for (int jq = 0; jq < 4; ++jq) Lpart[w * 64 + 16 * jq + l15] = ls[jq];
  }
  __syncthreads();
  if (tid < 64)
    Lq[tid] = Lpart[tid] + Lpart[64 + tid] + Lpart[128 + tid] + Lpart[192 + tid];
  __syncthreads();

  // epilogue: O rows q = 16jq+4quad+r, cols d = 16w+l15; gate + store
#pragma unroll
  for (int jq = 0; jq < 4; ++jq) {
#pragma unroll
    for (int r = 0; r < 4; ++r) {
      int qloc = 16 * jq + 4 * quad + r;
      float lv = Lq[qloc];
      float gv = b2f(((const unsigned short*)gc)[
          ((size_t)((b * 16 + h) * 1024) + qt * 64 + qloc) * 64 + 16 * w + l15]);
      size_t row = (size_t)(b * NN + qt * 64 + qloc);
      gated[row * 1024 + h * 64 + 16 * w + l15] = f2b(oacc[jq][r] / lv * gv);
    }
  }
}

// ---------------------------------------------------------------------------
extern "C" void kernel_launch(void* const* d_in, const int* in_sizes, int n_in,
                              void* d_out, int out_size, void* d_ws,
                              size_t ws_size, hipStream_t stream) {
  const float* x = (const float*)d_in[0];
  const float* Wq = (const float*)d_in[1];
  const float* Wkv = (const float*)d_in[2];
  const float* Wg = (const float*)d_in[3];
  const float* bg = (const float*)d_in[4];
  const float* Wo = (const float*)d_in[5];
  float* out = (float*)d_out;

  // ws layout (short elems): ~36.6 MB total
  short* ws = (short*)d_ws;
  short* xb = ws;                     // 4.19M (x bf16; later aliased as gated)
  short* WcT = xb + 4194304;          // 2.62M (W^T combined: q|g|kv rows)
  short* WoT = WcT + 2621440;         // 1.05M
  short* qc = WoT + 1048576;          // 4.19M  q[b,h,tok,d]
  short* gc = qc + 4194304;           // 4.19M  gate[b,h,tok,d]
  short* kc = gc + 4194304;           // 1.05M  k[b,kvh,tok,d]
  short* vtw = kc + 1048576;          // 1.05M  v^T[b,kvh,d,tok]
  float* bias_f32 = (float*)(vtw + 1048576);  // 2560 f32

  dim3 blk(256);
  // weight transposes + bias + x-convert, one dispatch
  transpose_all<<<dim3(16, 16, 6), blk, 0, stream>>>(Wq, Wkv, Wg, Wo, bg, x,
                                                     WcT, WoT, bias_f32, xb);
  // fused q|gate|kv projection (outputs diverted to compact layouts)
  gemm_proj<<<dim3(20, 64), blk, 0, stream>>>(xb, WcT, bias_f32, qc, gc, kc, vtw);
  // attention + gate -> gated (aliases xb; xb no longer needed)
  attn_mfma8<<<dim3(16, 64), blk, 0, stream>>>(qc, gc, kc, vtw, (unsigned short*)xb);
  // output projection
  gemm_out<<<dim3(16, 64), blk, 0, stream>>>(xb, WoT, out);
}